// Round 5
// baseline (454.993 us; speedup 1.0000x reference)
//
#include <hip/hip_runtime.h>
#include <math.h>

#define CH   256
#define C8K  32
#define NPOS 4096
#define BQ   4

typedef __attribute__((ext_vector_type(8))) short bf16x8;   // 8 bf16 = 4 VGPR
typedef __attribute__((ext_vector_type(4))) float f32x4;

__device__ __forceinline__ unsigned short f2bf(float f) {   // RNE float->bf16
    unsigned int u = __float_as_uint(f);
    u = (u + 0x7FFFu + ((u >> 16) & 1u)) >> 16;
    return (unsigned short)u;
}
__device__ __forceinline__ float bf2f(unsigned int h) {
    return __uint_as_float(h << 16);
}

// ---------------------------------------------------------------------------
// prep_w: stack Wq(32x256)|Wk(32x256)|Wv(256x256) fp32 -> Whi/Wlo [320][256]
// bf16 (hi/lo split). grid 80 x 256 threads x 4 elems.
// ---------------------------------------------------------------------------
__global__ void prep_w(const float* __restrict__ Wq, const float* __restrict__ Wk,
                       const float* __restrict__ Wv,
                       unsigned short* __restrict__ Whi, unsigned short* __restrict__ Wlo)
{
    const int idx  = blockIdx.x * 256 + threadIdx.x;   // 0..20479
    const int e0   = idx * 4;
    const int row  = e0 >> 8;
    const int col  = e0 & 255;
    const float* src;
    if (row < 32)       src = Wq + row * 256 + col;
    else if (row < 64)  src = Wk + (row - 32) * 256 + col;
    else                src = Wv + (row - 64) * 256 + col;
    const float4 v = *reinterpret_cast<const float4*>(src);
    unsigned short h[4], l[4];
    const float* pv = &v.x;
    #pragma unroll
    for (int i = 0; i < 4; ++i) {
        h[i] = f2bf(pv[i]);
        l[i] = f2bf(pv[i] - bf2f((unsigned int)h[i]));
    }
    uint2 ph, pl;
    ph.x = (unsigned)h[0] | ((unsigned)h[1] << 16);
    ph.y = (unsigned)h[2] | ((unsigned)h[3] << 16);
    pl.x = (unsigned)l[0] | ((unsigned)l[1] << 16);
    pl.y = (unsigned)l[2] | ((unsigned)l[3] << 16);
    *reinterpret_cast<uint2*>(Whi + e0) = ph;
    *reinterpret_cast<uint2*>(Wlo + e0) = pl;
}

// ---------------------------------------------------------------------------
// MFMA projection. grid (64 n-tiles, 4 b), block 256 (4 waves), NO LDS, no
// barriers. Wave w owns n-cols n0+w*16..+15; 20 row-tiles of 16 out-ch.
// D[out][n] = W[out][ch] @ x[ch][n]: A-frag = Whi/Wlo rows (global, L1-hot),
// B-frag = x fp32 loaded per-lane, split hi/lo bf16 in-register. 3-MFMA
// hi/lo split => q,k at ~fp32 accuracy. Outputs: Qhi/Qlo/Khi/Klo [b][n][32]
// (transposed, attn-fragment-ready), Vw [b][c][n] bf16.
// ---------------------------------------------------------------------------
__global__ __launch_bounds__(256, 1) void proj_kernel(
    const float* __restrict__ x1,
    const unsigned short* __restrict__ Whi, const unsigned short* __restrict__ Wlo,
    const float* __restrict__ bq, const float* __restrict__ bk,
    const float* __restrict__ bv,
    unsigned short* __restrict__ Qhi, unsigned short* __restrict__ Qlo,
    unsigned short* __restrict__ Khi, unsigned short* __restrict__ Klo,
    unsigned short* __restrict__ Vw)
{
    const int t      = threadIdx.x;
    const int l      = t & 63;
    const int w      = t >> 6;         // wave 0..3 -> n-col slice
    const int lane15 = l & 15;
    const int g      = l >> 4;         // 0..3
    const int b      = blockIdx.y;
    const int n0     = blockIdx.x * 64;
    const int ncol   = n0 + w * 16 + lane15;

    const float* xb = x1 + (size_t)b * CH * NPOS + ncol;

    f32x4 acc[20];
    #pragma unroll
    for (int rt = 0; rt < 20; ++rt) acc[rt] = (f32x4){0.f, 0.f, 0.f, 0.f};

    for (int ks = 0; ks < 8; ++ks) {
        // ---- B-frag: x[ch = ks*32 + g*8 + e][ncol], e = 0..7, split hi/lo ----
        float xv[8];
        #pragma unroll
        for (int e = 0; e < 8; ++e)
            xv[e] = xb[(size_t)(ks * 32 + g * 8 + e) * NPOS];
        bf16x8 bh, bl;
        #pragma unroll
        for (int e = 0; e < 8; ++e) {
            const unsigned short h = f2bf(xv[e]);
            bh[e] = (short)h;
            bl[e] = (short)f2bf(xv[e] - bf2f((unsigned int)h));
        }
        // ---- A-frags + MFMA over 20 row-tiles ----
        const unsigned short* wh = Whi + lane15 * 256 + ks * 32 + g * 8;
        const unsigned short* wl = Wlo + lane15 * 256 + ks * 32 + g * 8;
        #pragma unroll
        for (int rt = 0; rt < 20; ++rt) {
            const bf16x8 ah = *reinterpret_cast<const bf16x8*>(wh + rt * 16 * 256);
            const bf16x8 al = *reinterpret_cast<const bf16x8*>(wl + rt * 16 * 256);
            acc[rt] = __builtin_amdgcn_mfma_f32_16x16x32_bf16(ah, bh, acc[rt], 0, 0, 0);
            acc[rt] = __builtin_amdgcn_mfma_f32_16x16x32_bf16(ah, bl, acc[rt], 0, 0, 0);
            acc[rt] = __builtin_amdgcn_mfma_f32_16x16x32_bf16(al, bh, acc[rt], 0, 0, 0);
        }
    }

    // ---- epilogue: D[out = rt*16+4g+r][ncol]; add bias; route q/k/v ----
    #pragma unroll
    for (int rt = 0; rt < 20; ++rt) {
        const int ch0 = rt * 16 + g * 4;    // +r
        if (rt < 4) {
            // q (rt 0..1) / k (rt 2..3): hi/lo split, [n][32] layout, b64 writes
            const float* bias   = (rt < 2) ? bq : bk;
            unsigned short* dhi = (rt < 2) ? Qhi : Khi;
            unsigned short* dlo = (rt < 2) ? Qlo : Klo;
            const int c0 = ch0 - (rt < 2 ? 0 : 32);
            unsigned short h[4], lo[4];
            #pragma unroll
            for (int r = 0; r < 4; ++r) {
                const float val = acc[rt][r] + bias[c0 + r];
                h[r]  = f2bf(val);
                lo[r] = f2bf(val - bf2f((unsigned int)h[r]));
            }
            const size_t off = ((size_t)b * NPOS + ncol) * C8K + c0;
            uint2 ph, pl;
            ph.x = (unsigned)h[0]  | ((unsigned)h[1]  << 16);
            ph.y = (unsigned)h[2]  | ((unsigned)h[3]  << 16);
            pl.x = (unsigned)lo[0] | ((unsigned)lo[1] << 16);
            pl.y = (unsigned)lo[2] | ((unsigned)lo[3] << 16);
            *reinterpret_cast<uint2*>(dhi + off) = ph;
            *reinterpret_cast<uint2*>(dlo + off) = pl;
        } else {
            // v: ch = ch0-64+r, layout [c][n] bf16
            const int c0 = ch0 - 64;
            #pragma unroll
            for (int r = 0; r < 4; ++r) {
                const float val = acc[rt][r] + bv[c0 + r];
                Vw[((size_t)b * CH + c0 + r) * NPOS + ncol] = f2bf(val);
            }
        }
    }
}

// ---------------------------------------------------------------------------
// MFMA flash attention. grid 256 = (4 b) x (64 m-tiles of 64), block 512
// (8 waves). Wave w: m-half mh=w>>2 (32 m's), n-slot ns=w&3 (16 n's).
// No max-subtraction (|S| <~ 35 << 88: fp32-exp safe; bf16 P range safe).
// Per key-tile: ALL next-tile global loads (K frags + V tile) issued right
// after barrier A into shadow regs (T14 double-buffer -> barrier-drain at B
// finds them mostly complete); S' = mfma(A=K,B=Q) x3 hi/lo; exp fp32;
// P->bf16 b64 to LDS; Vt written from regs loaded LAST tile; PV under
// setprio(1). 2 barriers/tile. Static LDS 47360 B, stride 72 ushorts
// (9x16B, odd) -> conflict-free b128.
// ---------------------------------------------------------------------------
__global__ __launch_bounds__(512, 2) void attn_kernel(
    const unsigned short* __restrict__ Qhi, const unsigned short* __restrict__ Qlo,
    const unsigned short* __restrict__ Khi, const unsigned short* __restrict__ Klo,
    const unsigned short* __restrict__ Vw,  const float* __restrict__ x1,
    const float* __restrict__ gamma, float* __restrict__ out)
{
    __shared__ __align__(16) unsigned char smem[47360];
    float*          smWave = (float*)smem;                        // [8][32]
    float*          smInv  = (float*)(smem + 1024);               // [64]
    unsigned short* Vt     = (unsigned short*)(smem + 1280);      // [256][72] bf16
    unsigned short* Pt     = (unsigned short*)(smem + 1280 + 36864); // [64][72]
    unsigned short* Ot     = Vt;                                  // epilogue alias

    const int t      = threadIdx.x;
    const int l      = t & 63;
    const int w      = t >> 6;        // wave 0..7
    const int ns     = w & 3;         // n-slot (16 keys)
    const int mh     = w >> 2;        // m-half (32 queries)
    const int lane15 = l & 15;
    const int g      = l >> 4;        // 0..3

    const int b  = blockIdx.x >> 6;
    const int m0 = (blockIdx.x & 63) << 6;

    const size_t qkBase = (size_t)b * NPOS * C8K;

    // ---- Q fragments in registers, reused across all 64 key-tiles ----
    bf16x8 qh[2], ql[2];
    #pragma unroll
    for (int j = 0; j < 2; ++j) {
        const size_t off = qkBase + (size_t)(m0 + (mh * 2 + j) * 16 + lane15) * C8K + g * 8;
        qh[j] = *reinterpret_cast<const bf16x8*>(Qhi + off);
        ql[j] = *reinterpret_cast<const bf16x8*>(Qlo + off);
    }
    // ---- K fragment base (n = n0 + ns*16 + lane15) ----
    const size_t kOffBase = qkBase + (size_t)(ns * 16 + lane15) * C8K + g * 8;
    // V staging mapping: vcq = t>>3 (0..63), vng = t&7
    const int vcq = t >> 3, vng = t & 7;
    const unsigned short* vsrcBase = Vw + (size_t)b * CH * NPOS + vng * 8;

    // ---- prologue: tile-0 K frags + V tile into current regs ----
    bf16x8 kh = *reinterpret_cast<const bf16x8*>(Khi + kOffBase);
    bf16x8 kl = *reinterpret_cast<const bf16x8*>(Klo + kOffBase);
    uint4 vc[4];
    #pragma unroll
    for (int i = 0; i < 4; ++i)
        vc[i] = *reinterpret_cast<const uint4*>(vsrcBase + (size_t)(vcq + 64 * i) * NPOS);

    f32x4 acc[2][4];   // [j][ct]: D[m = mh*32+j*16+g*4+r][c = ns*64+ct*16+lane15]
    #pragma unroll
    for (int j = 0; j < 2; ++j)
        #pragma unroll
        for (int ct = 0; ct < 4; ++ct)
            acc[j][ct] = (f32x4){0.f, 0.f, 0.f, 0.f};
    float psum[2] = {0.f, 0.f};

    for (int nt = 0; nt < 64; ++nt) {
        const int n0 = nt << 6;
        __syncthreads();   // A: previous PV finished reading Pt/Vt

        // ---- issue ALL next-tile loads now (drained at B, covered by S) ----
        const int nn = (nt < 63) ? (n0 + 64) : n0;
        bf16x8 knh = *reinterpret_cast<const bf16x8*>(Khi + kOffBase + (size_t)nn * C8K);
        bf16x8 knl = *reinterpret_cast<const bf16x8*>(Klo + kOffBase + (size_t)nn * C8K);
        uint4 vn[4];
        #pragma unroll
        for (int i = 0; i < 4; ++i)
            vn[i] = *reinterpret_cast<const uint4*>(
                vsrcBase + (size_t)(vcq + 64 * i) * NPOS + nn);

        // ---- write V tile from regs loaded last tile ----
        #pragma unroll
        for (int i = 0; i < 4; ++i)
            *reinterpret_cast<uint4*>(Vt + (vcq + 64 * i) * 72 + vng * 8) = vc[i];

        // ---- S' tiles: D[n_local][m] = sum_ch K[ch][n] Q[ch][m], hi/lo x3 ----
        float pe[2][4];
        #pragma unroll
        for (int j = 0; j < 2; ++j) {
            f32x4 s = (f32x4){0.f, 0.f, 0.f, 0.f};
            s = __builtin_amdgcn_mfma_f32_16x16x32_bf16(kh, qh[j], s, 0, 0, 0);
            s = __builtin_amdgcn_mfma_f32_16x16x32_bf16(kh, ql[j], s, 0, 0, 0);
            s = __builtin_amdgcn_mfma_f32_16x16x32_bf16(kl, qh[j], s, 0, 0, 0);
            #pragma unroll
            for (int r = 0; r < 4; ++r) {
                const float e = __expf(s[r]);
                pe[j][r] = e;
                psum[j] += e;
            }
        }
        // ---- pack P -> bf16: Pt[m=(mh*2+j)*16+lane15][n= ns*16+g*4+{0..3}] ----
        #pragma unroll
        for (int j = 0; j < 2; ++j) {
            uint2 pk;
            pk.x = (unsigned)f2bf(pe[j][0]) | ((unsigned)f2bf(pe[j][1]) << 16);
            pk.y = (unsigned)f2bf(pe[j][2]) | ((unsigned)f2bf(pe[j][3]) << 16);
            *reinterpret_cast<uint2*>(
                Pt + ((mh * 2 + j) * 16 + lane15) * 72 + ns * 16 + g * 4) = pk;
        }
        __syncthreads();   // B: Pt + Vt ready (next-tile loads drain here)

        // ---- PV: acc[m][c] += sum_n P[m][n] V[c][n] ----
        __builtin_amdgcn_s_setprio(1);
        #pragma unroll
        for (int ks = 0; ks < 2; ++ks) {
            bf16x8 pa[2], vb[4];
            #pragma unroll
            for (int j = 0; j < 2; ++j)
                pa[j] = *reinterpret_cast<const bf16x8*>(
                    Pt + (mh * 32 + j * 16 + lane15) * 72 + ks * 32 + g * 8);
            #pragma unroll
            for (int ct = 0; ct < 4; ++ct)
                vb[ct] = *reinterpret_cast<const bf16x8*>(
                    Vt + (ns * 64 + ct * 16 + lane15) * 72 + ks * 32 + g * 8);
            #pragma unroll
            for (int j = 0; j < 2; ++j)
                #pragma unroll
                for (int ct = 0; ct < 4; ++ct)
                    acc[j][ct] = __builtin_amdgcn_mfma_f32_16x16x32_bf16(
                        pa[j], vb[ct], acc[j][ct], 0, 0, 0);
        }
        __builtin_amdgcn_s_setprio(0);

        // ---- rotate double-buffered regs (SSA renames, no copies) ----
        kh = knh; kl = knl;
        #pragma unroll
        for (int i = 0; i < 4; ++i) vc[i] = vn[i];
    }

    // ---- denominator: reduce psum over g (shfl), combine n-slots via LDS ----
    #pragma unroll
    for (int j = 0; j < 2; ++j) {
        float v = psum[j];
        v += __shfl_xor(v, 16, 64);
        v += __shfl_xor(v, 32, 64);
        psum[j] = v;
    }
    if (l < 16) {
        #pragma unroll
        for (int j = 0; j < 2; ++j)
            smWave[w * 32 + j * 16 + lane15] = psum[j];
    }
    __syncthreads();
    if (t < 64) {
        const int mh2 = t >> 5, ml = t & 31;
        const float d = smWave[(mh2 * 4 + 0) * 32 + ml] + smWave[(mh2 * 4 + 1) * 32 + ml]
                      + smWave[(mh2 * 4 + 2) * 32 + ml] + smWave[(mh2 * 4 + 3) * 32 + ml];
        smInv[t] = 1.f / d;
    }
    __syncthreads();

    // ---- normalize, stash transposed (Ot[c][m], bf16, aliases dead Vt) ----
    #pragma unroll
    for (int j = 0; j < 2; ++j) {
        const float4 inv4 = *reinterpret_cast<const float4*>(smInv + mh * 32 + j * 16 + g * 4);
        #pragma unroll
        for (int ct = 0; ct < 4; ++ct) {
            const int c = ns * 64 + ct * 16 + lane15;
            const f32x4 a = acc[j][ct];
            uint2 pk;
            pk.x = (unsigned)f2bf(a[0] * inv4.x) | ((unsigned)f2bf(a[1] * inv4.y) << 16);
            pk.y = (unsigned)f2bf(a[2] * inv4.z) | ((unsigned)f2bf(a[3] * inv4.w) << 16);
            *reinterpret_cast<uint2*>(Ot + c * 72 + mh * 32 + j * 16 + g * 4) = pk;
        }
    }
    __syncthreads();

    // ---- fused out = gamma * att + x1, coalesced ----
    const float gm = gamma[0];
    {
        const int mq = t & 15, c0 = t >> 4;   // c0 0..31
        #pragma unroll 4
        for (int i = 0; i < 8; ++i) {
            const int c = c0 + (i << 5);
            const size_t off = ((size_t)(b * CH + c)) * NPOS + m0 + mq * 4;
            const uint2 pk = *reinterpret_cast<const uint2*>(Ot + c * 72 + mq * 4);
            const float4 xv = *reinterpret_cast<const float4*>(x1 + off);
            float4 ov;
            ov.x = gm * bf2f(pk.x & 0xFFFFu)  + xv.x;
            ov.y = gm * bf2f(pk.x >> 16)      + xv.y;
            ov.z = gm * bf2f(pk.y & 0xFFFFu)  + xv.z;
            ov.w = gm * bf2f(pk.y >> 16)      + xv.w;
            *reinterpret_cast<float4*>(out + off) = ov;
        }
    }
}

// ---------------------------------------------------------------------------
extern "C" void kernel_launch(void* const* d_in, const int* in_sizes, int n_in,
                              void* d_out, int out_size, void* d_ws, size_t ws_size,
                              hipStream_t stream)
{
    const float* x1    = (const float*)d_in[0];
    // d_in[1] = x2 : unused by the reference
    const float* Wq    = (const float*)d_in[2];
    const float* bq    = (const float*)d_in[3];
    const float* Wk    = (const float*)d_in[4];
    const float* bk    = (const float*)d_in[5];
    const float* Wv    = (const float*)d_in[6];
    const float* bv    = (const float*)d_in[7];
    const float* gamma = (const float*)d_in[8];
    float* out = (float*)d_out;

    // workspace (ushort elems):
    //   Qhi|Qlo|Khi|Klo each 4*4096*32 = 524288
    //   Vw 4*256*4096 = 4194304
    //   Whi|Wlo each 320*256 = 81920
    unsigned short* ws  = (unsigned short*)d_ws;
    const size_t QK     = (size_t)BQ * NPOS * C8K;
    unsigned short* Qhi = ws;
    unsigned short* Qlo = ws + QK;
    unsigned short* Khi = ws + 2 * QK;
    unsigned short* Klo = ws + 3 * QK;
    unsigned short* Vw  = ws + 4 * QK;
    unsigned short* Whi = Vw + (size_t)BQ * CH * NPOS;
    unsigned short* Wlo = Whi + 320 * 256;

    prep_w<<<dim3(80), 256, 0, stream>>>(Wq, Wk, Wv, Whi, Wlo);

    proj_kernel<<<dim3(64, BQ), 256, 0, stream>>>(
        x1, Whi, Wlo, bq, bk, bv, Qhi, Qlo, Khi, Klo, Vw);

    attn_kernel<<<dim3(256), 512, 0, stream>>>(
        Qhi, Qlo, Khi, Klo, Vw, x1, gamma, out);
}

// Round 7
// 304.933 us; speedup vs baseline: 1.4921x; 1.4921x over previous
//
#include <hip/hip_runtime.h>
#include <math.h>

#define CH   256
#define C8K  32
#define NPOS 4096
#define BQ   4

typedef __attribute__((ext_vector_type(8))) short bf16x8;   // 8 bf16 = 4 VGPR
typedef __attribute__((ext_vector_type(4))) float f32x4;

__device__ __forceinline__ unsigned short f2bf(float f) {   // RNE float->bf16
    unsigned int u = __float_as_uint(f);
    u = (u + 0x7FFFu + ((u >> 16) & 1u)) >> 16;
    return (unsigned short)u;
}
__device__ __forceinline__ float bf2f(unsigned int h) {
    return __uint_as_float(h << 16);
}

// ---------------------------------------------------------------------------
// prep_w: stack Wq(32x256)|Wk(32x256)|Wv(256x256) fp32 -> Whi/Wlo [320][256]
// bf16 (hi/lo split). grid 80 x 256 threads x 4 elems.
// ---------------------------------------------------------------------------
__global__ void prep_w(const float* __restrict__ Wq, const float* __restrict__ Wk,
                       const float* __restrict__ Wv,
                       unsigned short* __restrict__ Whi, unsigned short* __restrict__ Wlo)
{
    const int idx  = blockIdx.x * 256 + threadIdx.x;   // 0..20479
    const int e0   = idx * 4;
    const int row  = e0 >> 8;
    const int col  = e0 & 255;
    const float* src;
    if (row < 32)       src = Wq + row * 256 + col;
    else if (row < 64)  src = Wk + (row - 32) * 256 + col;
    else                src = Wv + (row - 64) * 256 + col;
    const float4 v = *reinterpret_cast<const float4*>(src);
    unsigned short h[4], l[4];
    const float* pv = &v.x;
    #pragma unroll
    for (int i = 0; i < 4; ++i) {
        h[i] = f2bf(pv[i]);
        l[i] = f2bf(pv[i] - bf2f((unsigned int)h[i]));
    }
    uint2 ph, pl;
    ph.x = (unsigned)h[0] | ((unsigned)h[1] << 16);
    ph.y = (unsigned)h[2] | ((unsigned)h[3] << 16);
    pl.x = (unsigned)l[0] | ((unsigned)l[1] << 16);
    pl.y = (unsigned)l[2] | ((unsigned)l[3] << 16);
    *reinterpret_cast<uint2*>(Whi + e0) = ph;
    *reinterpret_cast<uint2*>(Wlo + e0) = pl;
}

// ---------------------------------------------------------------------------
// MFMA projection. grid (64 n-tiles, 4 b), block 256 (4 waves), NO LDS.
// Wave w owns n-cols n0+w*16..+15. All 64 x-values per thread loaded in the
// PROLOGUE (one latency hit), converted to bf16 hi/lo once; ks-loop is pure
// W-frag loads + MFMA. 3-MFMA hi/lo split => q,k at ~fp32 accuracy.
// Outputs: Qhi/Qlo/Khi/Klo [b][n][32] (attn-fragment-ready), Vw [b][c][n].
// ---------------------------------------------------------------------------
__global__ __launch_bounds__(256, 1) void proj_kernel(
    const float* __restrict__ x1,
    const unsigned short* __restrict__ Whi, const unsigned short* __restrict__ Wlo,
    const float* __restrict__ bq, const float* __restrict__ bk,
    const float* __restrict__ bv,
    unsigned short* __restrict__ Qhi, unsigned short* __restrict__ Qlo,
    unsigned short* __restrict__ Khi, unsigned short* __restrict__ Klo,
    unsigned short* __restrict__ Vw)
{
    const int t      = threadIdx.x;
    const int l      = t & 63;
    const int w      = t >> 6;         // wave 0..3 -> n-col slice
    const int lane15 = l & 15;
    const int g      = l >> 4;         // 0..3
    const int b      = blockIdx.y;
    const int n0     = blockIdx.x * 64;
    const int ncol   = n0 + w * 16 + lane15;

    const float* xb = x1 + (size_t)b * CH * NPOS + ncol;

    // ---- prologue: load this thread's 64 x values (ch = ks*32+g*8+e) ----
    float xv[64];
    #pragma unroll
    for (int ks = 0; ks < 8; ++ks)
        #pragma unroll
        for (int e = 0; e < 8; ++e)
            xv[ks * 8 + e] = xb[(size_t)(ks * 32 + g * 8 + e) * NPOS];

    bf16x8 bh[8], bl[8];
    #pragma unroll
    for (int ks = 0; ks < 8; ++ks)
        #pragma unroll
        for (int e = 0; e < 8; ++e) {
            const float f = xv[ks * 8 + e];
            const unsigned short h = f2bf(f);
            bh[ks][e] = (short)h;
            bl[ks][e] = (short)f2bf(f - bf2f((unsigned int)h));
        }

    f32x4 acc[20];
    #pragma unroll
    for (int rt = 0; rt < 20; ++rt) acc[rt] = (f32x4){0.f, 0.f, 0.f, 0.f};

    for (int ks = 0; ks < 8; ++ks) {
        const unsigned short* wh = Whi + lane15 * 256 + ks * 32 + g * 8;
        const unsigned short* wl = Wlo + lane15 * 256 + ks * 32 + g * 8;
        #pragma unroll
        for (int rt = 0; rt < 20; ++rt) {
            const bf16x8 ah = *reinterpret_cast<const bf16x8*>(wh + rt * 16 * 256);
            const bf16x8 al = *reinterpret_cast<const bf16x8*>(wl + rt * 16 * 256);
            acc[rt] = __builtin_amdgcn_mfma_f32_16x16x32_bf16(ah, bh[ks], acc[rt], 0, 0, 0);
            acc[rt] = __builtin_amdgcn_mfma_f32_16x16x32_bf16(ah, bl[ks], acc[rt], 0, 0, 0);
            acc[rt] = __builtin_amdgcn_mfma_f32_16x16x32_bf16(al, bh[ks], acc[rt], 0, 0, 0);
        }
    }

    // ---- epilogue: D[out = rt*16+4g+r][ncol]; add bias; route q/k/v ----
    #pragma unroll
    for (int rt = 0; rt < 20; ++rt) {
        const int ch0 = rt * 16 + g * 4;    // +r
        if (rt < 4) {
            const float* bias   = (rt < 2) ? bq : bk;
            unsigned short* dhi = (rt < 2) ? Qhi : Khi;
            unsigned short* dlo = (rt < 2) ? Qlo : Klo;
            const int c0 = ch0 - (rt < 2 ? 0 : 32);
            unsigned short h[4], lo[4];
            #pragma unroll
            for (int r = 0; r < 4; ++r) {
                const float val = acc[rt][r] + bias[c0 + r];
                h[r]  = f2bf(val);
                lo[r] = f2bf(val - bf2f((unsigned int)h[r]));
            }
            const size_t off = ((size_t)b * NPOS + ncol) * C8K + c0;
            uint2 ph, pl;
            ph.x = (unsigned)h[0]  | ((unsigned)h[1]  << 16);
            ph.y = (unsigned)h[2]  | ((unsigned)h[3]  << 16);
            pl.x = (unsigned)lo[0] | ((unsigned)lo[1] << 16);
            pl.y = (unsigned)lo[2] | ((unsigned)lo[3] << 16);
            *reinterpret_cast<uint2*>(dhi + off) = ph;
            *reinterpret_cast<uint2*>(dlo + off) = pl;
        } else {
            const int c0 = ch0 - 64;
            #pragma unroll
            for (int r = 0; r < 4; ++r) {
                const float val = acc[rt][r] + bv[c0 + r];
                Vw[((size_t)b * CH + c0 + r) * NPOS + ncol] = f2bf(val);
            }
        }
    }
}

// ---------------------------------------------------------------------------
// MFMA flash attention. grid 256, block 512 (8 waves). XCD swizzle: wg&7 =
// XCD, 2 XCDs per batch -> per-XCD working set (K hi/lo 1MB + V 2MB + Q) < 4MB
// L2. Wave w: m-half mh=w>>2, n-slot ns=w&3. No max-subtraction (|S|<~35).
// Per key-tile: after barrier A issue V-tile loads + next-tile K-frag loads
// (T14; covered by S phase); S' = mfma(A=K,B=Q) x3 hi/lo; exp fp32; P->bf16
// to LDS; Vt written after S (vmcnt covered); barrier B; PV under setprio.
// 2 barriers/tile. Static LDS 47360 B, stride 72 ushorts (9x16B, odd).
// __launch_bounds__(512,1): grid=1 block/CU anyway; avoids the 128-VGPR
// cliff that spilled round 5 (577MB scratch writes).
// ---------------------------------------------------------------------------
__global__ __launch_bounds__(512, 1) void attn_kernel(
    const unsigned short* __restrict__ Qhi, const unsigned short* __restrict__ Qlo,
    const unsigned short* __restrict__ Khi, const unsigned short* __restrict__ Klo,
    const unsigned short* __restrict__ Vw,  const float* __restrict__ x1,
    const float* __restrict__ gamma, float* __restrict__ out)
{
    __shared__ __align__(16) unsigned char smem[47360];
    float*          smWave = (float*)smem;                        // [8][32]
    float*          smInv  = (float*)(smem + 1024);               // [64]
    unsigned short* Vt     = (unsigned short*)(smem + 1280);      // [256][72] bf16
    unsigned short* Pt     = (unsigned short*)(smem + 1280 + 36864); // [64][72]
    unsigned short* Ot     = Vt;                                  // epilogue alias

    const int t      = threadIdx.x;
    const int l      = t & 63;
    const int w      = t >> 6;        // wave 0..7
    const int ns     = w & 3;         // n-slot (16 keys)
    const int mh     = w >> 2;        // m-half (32 queries)
    const int lane15 = l & 15;
    const int g      = l >> 4;        // 0..3

    // XCD-aware swizzle: wg%8 = XCD; each batch pinned to 2 XCDs.
    const int wg   = blockIdx.x;
    const int xcd  = wg & 7;
    const int slot = wg >> 3;                 // 0..31
    const int b    = xcd >> 1;                // 0..3
    const int mt   = ((xcd & 1) << 5) + slot; // 0..63
    const int m0   = mt << 6;

    const size_t qkBase = (size_t)b * NPOS * C8K;

    // ---- Q fragments in registers, reused across all 64 key-tiles ----
    bf16x8 qh[2], ql[2];
    #pragma unroll
    for (int j = 0; j < 2; ++j) {
        const size_t off = qkBase + (size_t)(m0 + (mh * 2 + j) * 16 + lane15) * C8K + g * 8;
        qh[j] = *reinterpret_cast<const bf16x8*>(Qhi + off);
        ql[j] = *reinterpret_cast<const bf16x8*>(Qlo + off);
    }
    // ---- K fragment base (n = n0 + ns*16 + lane15); prologue loads tile 0 ----
    const size_t kOffBase = qkBase + (size_t)(ns * 16 + lane15) * C8K + g * 8;
    bf16x8 kh = *reinterpret_cast<const bf16x8*>(Khi + kOffBase);
    bf16x8 kl = *reinterpret_cast<const bf16x8*>(Klo + kOffBase);

    // V staging mapping: vcq = t>>3 (0..63), vng = t&7
    const int vcq = t >> 3, vng = t & 7;
    const unsigned short* vsrcBase = Vw + (size_t)b * CH * NPOS + vng * 8;

    f32x4 acc[2][4];   // [j][ct]: D[m = mh*32+j*16+g*4+r][c = ns*64+ct*16+lane15]
    #pragma unroll
    for (int j = 0; j < 2; ++j)
        #pragma unroll
        for (int ct = 0; ct < 4; ++ct)
            acc[j][ct] = (f32x4){0.f, 0.f, 0.f, 0.f};
    float psum[2] = {0.f, 0.f};

    for (int nt = 0; nt < 64; ++nt) {
        const int n0 = nt << 6;
        __syncthreads();   // A: previous PV finished reading Pt/Vt

        // ---- issue V-tile loads + next-tile K-frag loads (covered by S) ----
        uint4 vld[4];
        #pragma unroll
        for (int i = 0; i < 4; ++i)
            vld[i] = *reinterpret_cast<const uint4*>(
                vsrcBase + (size_t)(vcq + 64 * i) * NPOS + n0);
        const int nn = (nt < 63) ? (n0 + 64) : n0;
        bf16x8 knh = *reinterpret_cast<const bf16x8*>(Khi + kOffBase + (size_t)nn * C8K);
        bf16x8 knl = *reinterpret_cast<const bf16x8*>(Klo + kOffBase + (size_t)nn * C8K);

        // ---- S' tiles: D[n_local][m] = sum_ch K[ch][n] Q[ch][m], hi/lo x3 ----
        float pe[2][4];
        __builtin_amdgcn_s_setprio(1);
        #pragma unroll
        for (int j = 0; j < 2; ++j) {
            f32x4 s = (f32x4){0.f, 0.f, 0.f, 0.f};
            s = __builtin_amdgcn_mfma_f32_16x16x32_bf16(kh, qh[j], s, 0, 0, 0);
            s = __builtin_amdgcn_mfma_f32_16x16x32_bf16(kh, ql[j], s, 0, 0, 0);
            s = __builtin_amdgcn_mfma_f32_16x16x32_bf16(kl, qh[j], s, 0, 0, 0);
            #pragma unroll
            for (int r = 0; r < 4; ++r) {
                const float e = __expf(s[r]);
                pe[j][r] = e;
                psum[j] += e;
            }
        }
        __builtin_amdgcn_s_setprio(0);
        // ---- pack P -> bf16: Pt[m=(mh*2+j)*16+lane15][n= ns*16+g*4+{0..3}] ----
        #pragma unroll
        for (int j = 0; j < 2; ++j) {
            uint2 pk;
            pk.x = (unsigned)f2bf(pe[j][0]) | ((unsigned)f2bf(pe[j][1]) << 16);
            pk.y = (unsigned)f2bf(pe[j][2]) | ((unsigned)f2bf(pe[j][3]) << 16);
            *reinterpret_cast<uint2*>(
                Pt + ((mh * 2 + j) * 16 + lane15) * 72 + ns * 16 + g * 4) = pk;
        }
        // ---- write V tile (loads landed under the S phase) ----
        #pragma unroll
        for (int i = 0; i < 4; ++i)
            *reinterpret_cast<uint4*>(Vt + (vcq + 64 * i) * 72 + vng * 8) = vld[i];
        __syncthreads();   // B: Pt + Vt ready

        // ---- PV: acc[m][c] += sum_n P[m][n] V[c][n] ----
        __builtin_amdgcn_s_setprio(1);
        #pragma unroll
        for (int ks = 0; ks < 2; ++ks) {
            bf16x8 pa[2], vb[4];
            #pragma unroll
            for (int j = 0; j < 2; ++j)
                pa[j] = *reinterpret_cast<const bf16x8*>(
                    Pt + (mh * 32 + j * 16 + lane15) * 72 + ks * 32 + g * 8);
            #pragma unroll
            for (int ct = 0; ct < 4; ++ct)
                vb[ct] = *reinterpret_cast<const bf16x8*>(
                    Vt + (ns * 64 + ct * 16 + lane15) * 72 + ks * 32 + g * 8);
            #pragma unroll
            for (int j = 0; j < 2; ++j)
                #pragma unroll
                for (int ct = 0; ct < 4; ++ct)
                    acc[j][ct] = __builtin_amdgcn_mfma_f32_16x16x32_bf16(
                        pa[j], vb[ct], acc[j][ct], 0, 0, 0);
        }
        __builtin_amdgcn_s_setprio(0);

        kh = knh; kl = knl;   // rotate prefetched K frags (SSA rename)
    }

    // ---- denominator: reduce psum over g (shfl), combine n-slots via LDS ----
    #pragma unroll
    for (int j = 0; j < 2; ++j) {
        float v = psum[j];
        v += __shfl_xor(v, 16, 64);
        v += __shfl_xor(v, 32, 64);
        psum[j] = v;
    }
    if (l < 16) {
        #pragma unroll
        for (int j = 0; j < 2; ++j)
            smWave[w * 32 + j * 16 + lane15] = psum[j];
    }
    __syncthreads();
    if (t < 64) {
        const int mh2 = t >> 5, ml = t & 31;
        const float d = smWave[(mh2 * 4 + 0) * 32 + ml] + smWave[(mh2 * 4 + 1) * 32 + ml]
                      + smWave[(mh2 * 4 + 2) * 32 + ml] + smWave[(mh2 * 4 + 3) * 32 + ml];
        smInv[t] = 1.f / d;
    }
    __syncthreads();

    // ---- normalize, stash transposed (Ot[c][m], bf16, aliases dead Vt) ----
    #pragma unroll
    for (int j = 0; j < 2; ++j) {
        const float4 inv4 = *reinterpret_cast<const float4*>(smInv + mh * 32 + j * 16 + g * 4);
        #pragma unroll
        for (int ct = 0; ct < 4; ++ct) {
            const int c = ns * 64 + ct * 16 + lane15;
            const f32x4 a = acc[j][ct];
            uint2 pk;
            pk.x = (unsigned)f2bf(a[0] * inv4.x) | ((unsigned)f2bf(a[1] * inv4.y) << 16);
            pk.y = (unsigned)f2bf(a[2] * inv4.z) | ((unsigned)f2bf(a[3] * inv4.w) << 16);
            *reinterpret_cast<uint2*>(Ot + c * 72 + mh * 32 + j * 16 + g * 4) = pk;
        }
    }
    __syncthreads();

    // ---- fused out = gamma * att + x1, coalesced ----
    const float gm = gamma[0];
    {
        const int mq = t & 15, c0 = t >> 4;   // c0 0..31
        #pragma unroll 4
        for (int i = 0; i < 8; ++i) {
            const int c = c0 + (i << 5);
            const size_t off = ((size_t)(b * CH + c)) * NPOS + m0 + mq * 4;
            const uint2 pk = *reinterpret_cast<const uint2*>(Ot + c * 72 + mq * 4);
            const float4 xv = *reinterpret_cast<const float4*>(x1 + off);
            float4 ov;
            ov.x = gm * bf2f(pk.x & 0xFFFFu)  + xv.x;
            ov.y = gm * bf2f(pk.x >> 16)      + xv.y;
            ov.z = gm * bf2f(pk.y & 0xFFFFu)  + xv.z;
            ov.w = gm * bf2f(pk.y >> 16)      + xv.w;
            *reinterpret_cast<float4*>(out + off) = ov;
        }
    }
}

// ---------------------------------------------------------------------------
extern "C" void kernel_launch(void* const* d_in, const int* in_sizes, int n_in,
                              void* d_out, int out_size, void* d_ws, size_t ws_size,
                              hipStream_t stream)
{
    const float* x1    = (const float*)d_in[0];
    // d_in[1] = x2 : unused by the reference
    const float* Wq    = (const float*)d_in[2];
    const float* bq    = (const float*)d_in[3];
    const float* Wk    = (const float*)d_in[4];
    const float* bk    = (const float*)d_in[5];
    const float* Wv    = (const float*)d_in[6];
    const float* bv    = (const float*)d_in[7];
    const float* gamma = (const float*)d_in[8];
    float* out = (float*)d_out;

    // workspace (ushort elems):
    //   Qhi|Qlo|Khi|Klo each 4*4096*32 = 524288
    //   Vw 4*256*4096 = 4194304
    //   Whi|Wlo each 320*256 = 81920
    unsigned short* ws  = (unsigned short*)d_ws;
    const size_t QK     = (size_t)BQ * NPOS * C8K;
    unsigned short* Qhi = ws;
    unsigned short* Qlo = ws + QK;
    unsigned short* Khi = ws + 2 * QK;
    unsigned short* Klo = ws + 3 * QK;
    unsigned short* Vw  = ws + 4 * QK;
    unsigned short* Whi = Vw + (size_t)BQ * CH * NPOS;
    unsigned short* Wlo = Whi + 320 * 256;

    prep_w<<<dim3(80), 256, 0, stream>>>(Wq, Wk, Wv, Whi, Wlo);

    proj_kernel<<<dim3(64, BQ), 256, 0, stream>>>(
        x1, Whi, Wlo, bq, bk, bv, Qhi, Qlo, Khi, Klo, Vw);

    attn_kernel<<<dim3(256), 512, 0, stream>>>(
        Qhi, Qlo, Khi, Klo, Vw, x1, gamma, out);
}

// Round 9
// 225.380 us; speedup vs baseline: 2.0188x; 1.3530x over previous
//
#include <hip/hip_runtime.h>
#include <math.h>

#define CH   256
#define C8K  32
#define NPOS 4096
#define BQ   4

typedef __attribute__((ext_vector_type(8))) short bf16x8;   // 8 bf16 = 4 VGPR
typedef __attribute__((ext_vector_type(4))) float f32x4;

__device__ __forceinline__ unsigned short f2bf(float f) {   // RNE float->bf16
    unsigned int u = __float_as_uint(f);
    u = (u + 0x7FFFu + ((u >> 16) & 1u)) >> 16;
    return (unsigned short)u;
}
__device__ __forceinline__ float bf2f(unsigned int h) {
    return __uint_as_float(h << 16);
}

// ---------------------------------------------------------------------------
// prep_w: stack Wq(32x256)|Wk(32x256)|Wv(256x256) fp32 -> Whi/Wlo [320][256]
// bf16 (hi/lo split). grid 80 x 256 threads x 4 elems.  (unchanged, R7)
// ---------------------------------------------------------------------------
__global__ void prep_w(const float* __restrict__ Wq, const float* __restrict__ Wk,
                       const float* __restrict__ Wv,
                       unsigned short* __restrict__ Whi, unsigned short* __restrict__ Wlo)
{
    const int idx  = blockIdx.x * 256 + threadIdx.x;   // 0..20479
    const int e0   = idx * 4;
    const int row  = e0 >> 8;
    const int col  = e0 & 255;
    const float* src;
    if (row < 32)       src = Wq + row * 256 + col;
    else if (row < 64)  src = Wk + (row - 32) * 256 + col;
    else                src = Wv + (row - 64) * 256 + col;
    const float4 v = *reinterpret_cast<const float4*>(src);
    unsigned short h[4], l[4];
    const float* pv = &v.x;
    #pragma unroll
    for (int i = 0; i < 4; ++i) {
        h[i] = f2bf(pv[i]);
        l[i] = f2bf(pv[i] - bf2f((unsigned int)h[i]));
    }
    uint2 ph, pl;
    ph.x = (unsigned)h[0] | ((unsigned)h[1] << 16);
    ph.y = (unsigned)h[2] | ((unsigned)h[3] << 16);
    pl.x = (unsigned)l[0] | ((unsigned)l[1] << 16);
    pl.y = (unsigned)l[2] | ((unsigned)l[3] << 16);
    *reinterpret_cast<uint2*>(Whi + e0) = ph;
    *reinterpret_cast<uint2*>(Wlo + e0) = pl;
}

// ---------------------------------------------------------------------------
// MFMA projection, LDS-staged. grid (64 n-tiles, 4 b), block 512 (8 waves =
// 2/SIMD). Wave w: n-slice ns=w&3 (16 cols), rt-half rh=w>>2 (10 row-tiles).
// x tile staged COALESCED (float4 along n) into LDS bf16 hi/lo [n][ch] in two
// 128-ch halves; row stride 136 ushorts (17x16B, odd) -> conflict-free b128
// fragment reads. ks-loop: 2 ds_read_b128 + 20 W-loads (L2-hot) + 30 MFMA.
// acc = 10x4 VGPR; no register crunch (R7 proj serialized on 64 strided
// x-loads + 320 W-loads at 1 wave/SIMD with 124 regs -> 135 us).
// ---------------------------------------------------------------------------
__global__ __launch_bounds__(512, 1) void proj_kernel(
    const float* __restrict__ x1,
    const unsigned short* __restrict__ Whi, const unsigned short* __restrict__ Wlo,
    const float* __restrict__ bq, const float* __restrict__ bk,
    const float* __restrict__ bv,
    unsigned short* __restrict__ Qhi, unsigned short* __restrict__ Qlo,
    unsigned short* __restrict__ Khi, unsigned short* __restrict__ Klo,
    unsigned short* __restrict__ Vw)
{
    __shared__ __align__(16) unsigned short xh[64 * 136];
    __shared__ __align__(16) unsigned short xl[64 * 136];

    const int t      = threadIdx.x;
    const int l      = t & 63;
    const int w      = t >> 6;         // wave 0..7
    const int ns     = w & 3;          // n-slice (16 cols)
    const int rh     = w >> 2;         // rt-half: rt = rh*10 .. rh*10+9
    const int lane15 = l & 15;
    const int g      = l >> 4;         // 0..3
    const int b      = blockIdx.y;
    const int n0     = blockIdx.x * 64;
    const int ncol   = n0 + ns * 16 + lane15;

    const int nq = t & 15, c0 = t >> 4;   // staging map: c0 in 0..31

    f32x4 acc[10];
    #pragma unroll
    for (int rtl = 0; rtl < 10; ++rtl) acc[rtl] = (f32x4){0.f, 0.f, 0.f, 0.f};

    for (int h = 0; h < 2; ++h) {
        if (h) __syncthreads();   // protect previous half's reads
        // ---- stage ch half [h*128, h*128+128) coalesced, convert hi/lo ----
        #pragma unroll
        for (int i = 0; i < 4; ++i) {
            const int ch = c0 + 32 * i;          // 0..127 within half
            const float4 v = *reinterpret_cast<const float4*>(
                x1 + ((size_t)(b * CH + h * 128 + ch) * NPOS) + n0 + nq * 4);
            #pragma unroll
            for (int r = 0; r < 4; ++r) {
                const int n = nq * 4 + r;
                const float f = (&v.x)[r];
                const unsigned short hi = f2bf(f);
                xh[n * 136 + ch] = hi;
                xl[n * 136 + ch] = f2bf(f - bf2f((unsigned int)hi));
            }
        }
        __syncthreads();

        // ---- K-loop over this half's 4 k-slices ----
        #pragma unroll
        for (int ks2 = 0; ks2 < 4; ++ks2) {
            const int ks = h * 4 + ks2;
            const bf16x8 bh = *reinterpret_cast<const bf16x8*>(
                xh + (ns * 16 + lane15) * 136 + ks2 * 32 + g * 8);
            const bf16x8 bl = *reinterpret_cast<const bf16x8*>(
                xl + (ns * 16 + lane15) * 136 + ks2 * 32 + g * 8);
            const unsigned short* wh =
                Whi + (size_t)(rh * 160 + lane15) * 256 + ks * 32 + g * 8;
            const unsigned short* wl =
                Wlo + (size_t)(rh * 160 + lane15) * 256 + ks * 32 + g * 8;
            #pragma unroll
            for (int rtl = 0; rtl < 10; ++rtl) {
                const bf16x8 ah = *reinterpret_cast<const bf16x8*>(wh + rtl * 16 * 256);
                const bf16x8 al = *reinterpret_cast<const bf16x8*>(wl + rtl * 16 * 256);
                acc[rtl] = __builtin_amdgcn_mfma_f32_16x16x32_bf16(ah, bh, acc[rtl], 0, 0, 0);
                acc[rtl] = __builtin_amdgcn_mfma_f32_16x16x32_bf16(ah, bl, acc[rtl], 0, 0, 0);
                acc[rtl] = __builtin_amdgcn_mfma_f32_16x16x32_bf16(al, bh, acc[rtl], 0, 0, 0);
            }
        }
    }

    // ---- epilogue: rt = rh*10+rtl; D[out = rt*16+4g+r][ncol]; route q/k/v ----
    #pragma unroll
    for (int rtl = 0; rtl < 10; ++rtl) {
        const int rt  = rh * 10 + rtl;
        const int ch0 = rt * 16 + g * 4;    // +r
        if (rt < 4) {
            const float* bias   = (rt < 2) ? bq : bk;
            unsigned short* dhi = (rt < 2) ? Qhi : Khi;
            unsigned short* dlo = (rt < 2) ? Qlo : Klo;
            const int c0q = ch0 - (rt < 2 ? 0 : 32);
            unsigned short hq[4], lq[4];
            #pragma unroll
            for (int r = 0; r < 4; ++r) {
                const float val = acc[rtl][r] + bias[c0q + r];
                hq[r] = f2bf(val);
                lq[r] = f2bf(val - bf2f((unsigned int)hq[r]));
            }
            const size_t off = ((size_t)b * NPOS + ncol) * C8K + c0q;
            uint2 ph, pl;
            ph.x = (unsigned)hq[0] | ((unsigned)hq[1] << 16);
            ph.y = (unsigned)hq[2] | ((unsigned)hq[3] << 16);
            pl.x = (unsigned)lq[0] | ((unsigned)lq[1] << 16);
            pl.y = (unsigned)lq[2] | ((unsigned)lq[3] << 16);
            *reinterpret_cast<uint2*>(dhi + off) = ph;
            *reinterpret_cast<uint2*>(dlo + off) = pl;
        } else {
            const int cv = ch0 - 64;
            #pragma unroll
            for (int r = 0; r < 4; ++r) {
                const float val = acc[rtl][r] + bv[cv + r];
                Vw[((size_t)b * CH + cv + r) * NPOS + ncol] = f2bf(val);
            }
        }
    }
}

// ---------------------------------------------------------------------------
// MFMA flash attention — byte-identical to validated R7 kernel.
// ---------------------------------------------------------------------------
__global__ __launch_bounds__(512, 1) void attn_kernel(
    const unsigned short* __restrict__ Qhi, const unsigned short* __restrict__ Qlo,
    const unsigned short* __restrict__ Khi, const unsigned short* __restrict__ Klo,
    const unsigned short* __restrict__ Vw,  const float* __restrict__ x1,
    const float* __restrict__ gamma, float* __restrict__ out)
{
    __shared__ __align__(16) unsigned char smem[47360];
    float*          smWave = (float*)smem;                        // [8][32]
    float*          smInv  = (float*)(smem + 1024);               // [64]
    unsigned short* Vt     = (unsigned short*)(smem + 1280);      // [256][72] bf16
    unsigned short* Pt     = (unsigned short*)(smem + 1280 + 36864); // [64][72]
    unsigned short* Ot     = Vt;                                  // epilogue alias

    const int t      = threadIdx.x;
    const int l      = t & 63;
    const int w      = t >> 6;        // wave 0..7
    const int ns     = w & 3;         // n-slot (16 keys)
    const int mh     = w >> 2;        // m-half (32 queries)
    const int lane15 = l & 15;
    const int g      = l >> 4;        // 0..3

    // XCD-aware swizzle: wg%8 = XCD; each batch pinned to 2 XCDs.
    const int wg   = blockIdx.x;
    const int xcd  = wg & 7;
    const int slot = wg >> 3;                 // 0..31
    const int b    = xcd >> 1;                // 0..3
    const int mt   = ((xcd & 1) << 5) + slot; // 0..63
    const int m0   = mt << 6;

    const size_t qkBase = (size_t)b * NPOS * C8K;

    // ---- Q fragments in registers, reused across all 64 key-tiles ----
    bf16x8 qh[2], ql[2];
    #pragma unroll
    for (int j = 0; j < 2; ++j) {
        const size_t off = qkBase + (size_t)(m0 + (mh * 2 + j) * 16 + lane15) * C8K + g * 8;
        qh[j] = *reinterpret_cast<const bf16x8*>(Qhi + off);
        ql[j] = *reinterpret_cast<const bf16x8*>(Qlo + off);
    }
    // ---- K fragment base (n = n0 + ns*16 + lane15); prologue loads tile 0 ----
    const size_t kOffBase = qkBase + (size_t)(ns * 16 + lane15) * C8K + g * 8;
    bf16x8 kh = *reinterpret_cast<const bf16x8*>(Khi + kOffBase);
    bf16x8 kl = *reinterpret_cast<const bf16x8*>(Klo + kOffBase);

    // V staging mapping: vcq = t>>3 (0..63), vng = t&7
    const int vcq = t >> 3, vng = t & 7;
    const unsigned short* vsrcBase = Vw + (size_t)b * CH * NPOS + vng * 8;

    f32x4 acc[2][4];   // [j][ct]: D[m = mh*32+j*16+g*4+r][c = ns*64+ct*16+lane15]
    #pragma unroll
    for (int j = 0; j < 2; ++j)
        #pragma unroll
        for (int ct = 0; ct < 4; ++ct)
            acc[j][ct] = (f32x4){0.f, 0.f, 0.f, 0.f};
    float psum[2] = {0.f, 0.f};

    for (int nt = 0; nt < 64; ++nt) {
        const int n0 = nt << 6;
        __syncthreads();   // A: previous PV finished reading Pt/Vt

        // ---- issue V-tile loads + next-tile K-frag loads (covered by S) ----
        uint4 vld[4];
        #pragma unroll
        for (int i = 0; i < 4; ++i)
            vld[i] = *reinterpret_cast<const uint4*>(
                vsrcBase + (size_t)(vcq + 64 * i) * NPOS + n0);
        const int nn = (nt < 63) ? (n0 + 64) : n0;
        bf16x8 knh = *reinterpret_cast<const bf16x8*>(Khi + kOffBase + (size_t)nn * C8K);
        bf16x8 knl = *reinterpret_cast<const bf16x8*>(Klo + kOffBase + (size_t)nn * C8K);

        // ---- S' tiles: D[n_local][m] = sum_ch K[ch][n] Q[ch][m], hi/lo x3 ----
        float pe[2][4];
        __builtin_amdgcn_s_setprio(1);
        #pragma unroll
        for (int j = 0; j < 2; ++j) {
            f32x4 s = (f32x4){0.f, 0.f, 0.f, 0.f};
            s = __builtin_amdgcn_mfma_f32_16x16x32_bf16(kh, qh[j], s, 0, 0, 0);
            s = __builtin_amdgcn_mfma_f32_16x16x32_bf16(kh, ql[j], s, 0, 0, 0);
            s = __builtin_amdgcn_mfma_f32_16x16x32_bf16(kl, qh[j], s, 0, 0, 0);
            #pragma unroll
            for (int r = 0; r < 4; ++r) {
                const float e = __expf(s[r]);
                pe[j][r] = e;
                psum[j] += e;
            }
        }
        __builtin_amdgcn_s_setprio(0);
        // ---- pack P -> bf16: Pt[m=(mh*2+j)*16+lane15][n= ns*16+g*4+{0..3}] ----
        #pragma unroll
        for (int j = 0; j < 2; ++j) {
            uint2 pk;
            pk.x = (unsigned)f2bf(pe[j][0]) | ((unsigned)f2bf(pe[j][1]) << 16);
            pk.y = (unsigned)f2bf(pe[j][2]) | ((unsigned)f2bf(pe[j][3]) << 16);
            *reinterpret_cast<uint2*>(
                Pt + ((mh * 2 + j) * 16 + lane15) * 72 + ns * 16 + g * 4) = pk;
        }
        // ---- write V tile (loads landed under the S phase) ----
        #pragma unroll
        for (int i = 0; i < 4; ++i)
            *reinterpret_cast<uint4*>(Vt + (vcq + 64 * i) * 72 + vng * 8) = vld[i];
        __syncthreads();   // B: Pt + Vt ready

        // ---- PV: acc[m][c] += sum_n P[m][n] V[c][n] ----
        __builtin_amdgcn_s_setprio(1);
        #pragma unroll
        for (int ks = 0; ks < 2; ++ks) {
            bf16x8 pa[2], vb[4];
            #pragma unroll
            for (int j = 0; j < 2; ++j)
                pa[j] = *reinterpret_cast<const bf16x8*>(
                    Pt + (mh * 32 + j * 16 + lane15) * 72 + ks * 32 + g * 8);
            #pragma unroll
            for (int ct = 0; ct < 4; ++ct)
                vb[ct] = *reinterpret_cast<const bf16x8*>(
                    Vt + (ns * 64 + ct * 16 + lane15) * 72 + ks * 32 + g * 8);
            #pragma unroll
            for (int j = 0; j < 2; ++j)
                #pragma unroll
                for (int ct = 0; ct < 4; ++ct)
                    acc[j][ct] = __builtin_amdgcn_mfma_f32_16x16x32_bf16(
                        pa[j], vb[ct], acc[j][ct], 0, 0, 0);
        }
        __builtin_amdgcn_s_setprio(0);

        kh = knh; kl = knl;   // rotate prefetched K frags (SSA rename)
    }

    // ---- denominator: reduce psum over g (shfl), combine n-slots via LDS ----
    #pragma unroll
    for (int j = 0; j < 2; ++j) {
        float v = psum[j];
        v += __shfl_xor(v, 16, 64);
        v += __shfl_xor(v, 32, 64);
        psum[j] = v;
    }
    if (l < 16) {
        #pragma unroll
        for (int j = 0; j < 2; ++j)
            smWave[w * 32 + j * 16 + lane15] = psum[j];
    }
    __syncthreads();
    if (t < 64) {
        const int mh2 = t >> 5, ml = t & 31;
        const float d = smWave[(mh2 * 4 + 0) * 32 + ml] + smWave[(mh2 * 4 + 1) * 32 + ml]
                      + smWave[(mh2 * 4 + 2) * 32 + ml] + smWave[(mh2 * 4 + 3) * 32 + ml];
        smInv[t] = 1.f / d;
    }
    __syncthreads();

    // ---- normalize, stash transposed (Ot[c][m], bf16, aliases dead Vt) ----
    #pragma unroll
    for (int j = 0; j < 2; ++j) {
        const float4 inv4 = *reinterpret_cast<const float4*>(smInv + mh * 32 + j * 16 + g * 4);
        #pragma unroll
        for (int ct = 0; ct < 4; ++ct) {
            const int c = ns * 64 + ct * 16 + lane15;
            const f32x4 a = acc[j][ct];
            uint2 pk;
            pk.x = (unsigned)f2bf(a[0] * inv4.x) | ((unsigned)f2bf(a[1] * inv4.y) << 16);
            pk.y = (unsigned)f2bf(a[2] * inv4.z) | ((unsigned)f2bf(a[3] * inv4.w) << 16);
            *reinterpret_cast<uint2*>(Ot + c * 72 + mh * 32 + j * 16 + g * 4) = pk;
        }
    }
    __syncthreads();

    // ---- fused out = gamma * att + x1, coalesced ----
    const float gm = gamma[0];
    {
        const int mq = t & 15, c0 = t >> 4;   // c0 0..31
        #pragma unroll 4
        for (int i = 0; i < 8; ++i) {
            const int c = c0 + (i << 5);
            const size_t off = ((size_t)(b * CH + c)) * NPOS + m0 + mq * 4;
            const uint2 pk = *reinterpret_cast<const uint2*>(Ot + c * 72 + mq * 4);
            const float4 xv = *reinterpret_cast<const float4*>(x1 + off);
            float4 ov;
            ov.x = gm * bf2f(pk.x & 0xFFFFu)  + xv.x;
            ov.y = gm * bf2f(pk.x >> 16)      + xv.y;
            ov.z = gm * bf2f(pk.y & 0xFFFFu)  + xv.z;
            ov.w = gm * bf2f(pk.y >> 16)      + xv.w;
            *reinterpret_cast<float4*>(out + off) = ov;
        }
    }
}

// ---------------------------------------------------------------------------
extern "C" void kernel_launch(void* const* d_in, const int* in_sizes, int n_in,
                              void* d_out, int out_size, void* d_ws, size_t ws_size,
                              hipStream_t stream)
{
    const float* x1    = (const float*)d_in[0];
    // d_in[1] = x2 : unused by the reference
    const float* Wq    = (const float*)d_in[2];
    const float* bq    = (const float*)d_in[3];
    const float* Wk    = (const float*)d_in[4];
    const float* bk    = (const float*)d_in[5];
    const float* Wv    = (const float*)d_in[6];
    const float* bv    = (const float*)d_in[7];
    const float* gamma = (const float*)d_in[8];
    float* out = (float*)d_out;

    // workspace (ushort elems):
    //   Qhi|Qlo|Khi|Klo each 4*4096*32 = 524288
    //   Vw 4*256*4096 = 4194304
    //   Whi|Wlo each 320*256 = 81920
    unsigned short* ws  = (unsigned short*)d_ws;
    const size_t QK     = (size_t)BQ * NPOS * C8K;
    unsigned short* Qhi = ws;
    unsigned short* Qlo = ws + QK;
    unsigned short* Khi = ws + 2 * QK;
    unsigned short* Klo = ws + 3 * QK;
    unsigned short* Vw  = ws + 4 * QK;
    unsigned short* Whi = Vw + (size_t)BQ * CH * NPOS;
    unsigned short* Wlo = Whi + 320 * 256;

    prep_w<<<dim3(80), 256, 0, stream>>>(Wq, Wk, Wv, Whi, Wlo);

    proj_kernel<<<dim3(64, BQ), 512, 0, stream>>>(
        x1, Whi, Wlo, bq, bk, bv, Qhi, Qlo, Khi, Klo, Vw);

    attn_kernel<<<dim3(256), 512, 0, stream>>>(
        Qhi, Qlo, Khi, Klo, Vw, x1, gamma, out);
}